// Round 1
// baseline (809.676 us; speedup 1.0000x reference)
//
#include <hip/hip_runtime.h>
#include <stdint.h>

#define NPTS 2048
#define NBATCH 8
#define EMB 256
#define INNERD 64
#define KNNK 16
#define ROWS (NBATCH*NPTS)        // 16384 points
#define NROWS (ROWS*KNNK)         // 262144 point-neighbor rows

// ---------------- transpose w_att1 (64x256 -> 256x64) ----------------
__global__ __launch_bounds__(256) void k_transpose_w1(const float* __restrict__ w_att1,
                                                      float* __restrict__ w1t) {
    int t = blockIdx.x * 256 + threadIdx.x;   // 16384 total
    int c = t >> 8;      // 0..63   (row of w_att1)
    int j = t & 255;     // 0..255  (col of w_att1)
    w1t[j * 64 + c] = w_att1[c * 256 + j];
}

// ---------------- qkv = x @ w_qkv ----------------
// thread = row, blockIdx.y = which 64-col chunk (q / k / v)
__global__ __launch_bounds__(256) void k_qkv(const float* __restrict__ x,
                                             const float* __restrict__ w_qkv,
                                             float* __restrict__ q,
                                             float* __restrict__ kk,
                                             float* __restrict__ v) {
    const int row = blockIdx.x * 256 + threadIdx.x;   // 0..16383
    const int cc  = blockIdx.y;                        // 0..2
    float out[64];
#pragma unroll
    for (int c = 0; c < 64; ++c) out[c] = 0.f;
    const float* xr = x + (size_t)row * 256;
#pragma unroll 1
    for (int k8 = 0; k8 < 32; ++k8) {
        float4 a0 = *(const float4*)(xr + k8 * 8);
        float4 a1 = *(const float4*)(xr + k8 * 8 + 4);
        float xa[8] = {a0.x, a0.y, a0.z, a0.w, a1.x, a1.y, a1.z, a1.w};
#pragma unroll
        for (int k2 = 0; k2 < 8; ++k2) {
            const float* wrow = w_qkv + (size_t)(k8 * 8 + k2) * 192 + cc * 64;  // uniform -> s_load
#pragma unroll
            for (int c = 0; c < 64; ++c) out[c] = fmaf(xa[k2], wrow[c], out[c]);
        }
    }
    float* dst = (cc == 0) ? q : ((cc == 1) ? kk : v);
#pragma unroll
    for (int c4 = 0; c4 < 16; ++c4) {
        float4 o = {out[c4*4], out[c4*4+1], out[c4*4+2], out[c4*4+3]};
        *(float4*)(dst + (size_t)row * 64 + c4 * 4) = o;
    }
}

// ---------------- q <- q - k (elementwise, float4) ----------------
__global__ __launch_bounds__(256) void k_qmk(float* __restrict__ q,
                                             const float* __restrict__ kk) {
    int t = blockIdx.x * 256 + threadIdx.x;   // 262144 float4 groups
    float4 a = ((const float4*)q)[t];
    float4 b = ((const float4*)kk)[t];
    a.x -= b.x; a.y -= b.y; a.z -= b.z; a.w -= b.w;
    ((float4*)q)[t] = a;
}

// ---------------- KNN: top-16 of sim = 2*dot - d2i - d2j ----------------
// block per point, 256 threads, 8 candidates per thread in registers,
// 16 iterations of (local max -> LDS tree argmax -> mask winner).
// key = (monotone_f32_key(sim) << 32) | (0xFFFFFFFF - j)  => ties pick lower j,
// matching jax.lax.top_k.
__global__ __launch_bounds__(256) void k_knn(const float* __restrict__ pos,
                                             int* __restrict__ idxo) {
    __shared__ unsigned long long red[256];
    const int pid = blockIdx.x;          // 0..16383
    const int b   = pid >> 11;
    const int i   = pid & (NPTS - 1);
    const int t   = threadIdx.x;
    const float* pb = pos + (size_t)b * NPTS * 3;

    float xi = pb[i*3], yi = pb[i*3+1], zi = pb[i*3+2];
    float d2i = xi * xi;  d2i = fmaf(yi, yi, d2i);  d2i = fmaf(zi, zi, d2i);

    unsigned long long key[8];
#pragma unroll
    for (int m = 0; m < 8; ++m) {
        int j = m * 256 + t;
        float xj = pb[j*3], yj = pb[j*3+1], zj = pb[j*3+2];
        float d2j = xj * xj;  d2j = fmaf(yj, yj, d2j);  d2j = fmaf(zj, zj, d2j);
        float dot = xi * xj;  dot = fmaf(yi, yj, dot);  dot = fmaf(zi, zj, dot);
        float sim = 2.0f * dot - d2i - d2j;
        unsigned int u  = __float_as_uint(sim);
        unsigned int fk = (u & 0x80000000u) ? ~u : (u | 0x80000000u);
        key[m] = ((unsigned long long)fk << 32) | (unsigned int)(0xFFFFFFFFu - (unsigned)j);
    }

    int my = 0;
#pragma unroll 1
    for (int it = 0; it < 16; ++it) {
        unsigned long long best = key[0];
#pragma unroll
        for (int m = 1; m < 8; ++m) best = (key[m] > best) ? key[m] : best;
        red[t] = best;
        __syncthreads();
        for (int s = 128; s > 0; s >>= 1) {
            if (t < s) {
                unsigned long long o = red[t + s];
                if (o > red[t]) red[t] = o;
            }
            __syncthreads();
        }
        unsigned long long win = red[0];
        __syncthreads();
        int jw = (int)(0xFFFFFFFFu - (unsigned)(win & 0xFFFFFFFFu));
        if (t == (jw & 255)) {
            switch (jw >> 8) {     // static register index (avoid scratch)
                case 0: key[0] = 0ull; break;  case 1: key[1] = 0ull; break;
                case 2: key[2] = 0ull; break;  case 3: key[3] = 0ull; break;
                case 4: key[4] = 0ull; break;  case 5: key[5] = 0ull; break;
                case 6: key[6] = 0ull; break;  case 7: key[7] = 0ull; break;
            }
        }
        if (t == it) my = jw;
        // (no sync needed here: next write to red[t] happens after the sync above)
    }
    if (t < 16) idxo[pid * 16 + t] = b * NPTS + my;
}

// ---------------- fused: rpe MLP + vnn store + h + att MLP + softmax ----------------
// thread = one (point, neighbor) row. Weights are wave-uniform -> scalar path.
__global__ __launch_bounds__(256) void k_att(
    const float* __restrict__ qmk, const float* __restrict__ v,
    const float* __restrict__ pos, const int* __restrict__ idx,
    const float* __restrict__ w_pos1, const float* __restrict__ b_pos1,
    const float* __restrict__ w_pos2, const float* __restrict__ b_pos2,
    const float* __restrict__ w1t,  const float* __restrict__ b_att1,
    const float* __restrict__ w_att2, const float* __restrict__ b_att2,
    float* __restrict__ vnn, float* __restrict__ attn)
{
    const int row  = blockIdx.x * 256 + threadIdx.x;  // 0..262143
    const int p    = row >> 4;
    const int flat = idx[row];

    float rel0 = pos[flat*3]   - pos[p*3];
    float rel1 = pos[flat*3+1] - pos[p*3+1];
    float rel2 = pos[flat*3+2] - pos[p*3+2];

    // ---- rpe = relu(rel @ w_pos1 + b_pos1) @ w_pos2 + b_pos2 ----
    float acc[64];
#pragma unroll
    for (int c = 0; c < 64; ++c) acc[c] = b_pos2[c];
#pragma unroll 1
    for (int j = 0; j < 64; ++j) {
        float ph = fmaf(rel2, w_pos1[128 + j],
                   fmaf(rel1, w_pos1[64 + j],
                   fmaf(rel0, w_pos1[j], b_pos1[j])));
        ph = fmaxf(ph, 0.f);
        const float* w2r = w_pos2 + (size_t)j * 64;   // uniform -> s_load
#pragma unroll
        for (int c = 0; c < 64; ++c) acc[c] = fmaf(ph, w2r[c], acc[c]);
    }

    // ---- vnn = v[flat] + rpe  (store for k_agg) ----
#pragma unroll
    for (int c4 = 0; c4 < 16; ++c4) {
        float4 v4 = *(const float4*)(v + (size_t)flat * 64 + c4 * 4);
        float4 o = {v4.x + acc[c4*4], v4.y + acc[c4*4+1], v4.z + acc[c4*4+2], v4.w + acc[c4*4+3]};
        *(float4*)(vnn + (size_t)row * 64 + c4 * 4) = o;
    }

    // ---- h = (q-k)[flat] + rpe  (in place) ----
#pragma unroll
    for (int c4 = 0; c4 < 16; ++c4) {
        float4 d4 = *(const float4*)(qmk + (size_t)flat * 64 + c4 * 4);
        acc[c4*4]   += d4.x; acc[c4*4+1] += d4.y;
        acc[c4*4+2] += d4.z; acc[c4*4+3] += d4.w;
    }

    // ---- sim = relu(h @ w_att1 + b_att1) @ w_att2 + b_att2 ----
    float out[64];
#pragma unroll
    for (int c = 0; c < 64; ++c) out[c] = b_att2[c];
#pragma unroll 1
    for (int j = 0; j < 256; ++j) {
        const float* w1r = w1t + (size_t)j * 64;      // uniform -> s_load
        float h0 = b_att1[j], h1 = 0.f, h2 = 0.f, h3 = 0.f;
#pragma unroll
        for (int c = 0; c < 64; c += 4) {
            h0 = fmaf(acc[c],   w1r[c],   h0);
            h1 = fmaf(acc[c+1], w1r[c+1], h1);
            h2 = fmaf(acc[c+2], w1r[c+2], h2);
            h3 = fmaf(acc[c+3], w1r[c+3], h3);
        }
        float hid = fmaxf((h0 + h1) + (h2 + h3), 0.f);
        const float* w2r = w_att2 + (size_t)j * 64;   // uniform -> s_load
#pragma unroll
        for (int c = 0; c < 64; ++c) out[c] = fmaf(hid, w2r[c], out[c]);
    }

    // ---- softmax over channel dim (thread-local, 64 regs) ----
    float mx = out[0];
#pragma unroll
    for (int c = 1; c < 64; ++c) mx = fmaxf(mx, out[c]);
    float s0 = 0.f, s1 = 0.f, s2 = 0.f, s3 = 0.f;
#pragma unroll
    for (int c = 0; c < 64; c += 4) {
        out[c]   = __expf(out[c]   - mx); s0 += out[c];
        out[c+1] = __expf(out[c+1] - mx); s1 += out[c+1];
        out[c+2] = __expf(out[c+2] - mx); s2 += out[c+2];
        out[c+3] = __expf(out[c+3] - mx); s3 += out[c+3];
    }
    float inv = 1.0f / ((s0 + s1) + (s2 + s3));
#pragma unroll
    for (int c4 = 0; c4 < 16; ++c4) {
        float4 o = {out[c4*4] * inv, out[c4*4+1] * inv, out[c4*4+2] * inv, out[c4*4+3] * inv};
        *(float4*)(attn + (size_t)row * 64 + c4 * 4) = o;
    }
}

// ---------------- L2-normalize over neighbors + weighted agg ----------------
// wave per point, lane = channel; norm/agg reductions are loop-local per lane.
__global__ __launch_bounds__(256) void k_agg(const float* __restrict__ attn,
                                             const float* __restrict__ vnn,
                                             float* __restrict__ agg) {
    const int p = blockIdx.x * 4 + (threadIdx.x >> 6);
    const int c = threadIdx.x & 63;
    float an = 0.f, ag = 0.f;
#pragma unroll
    for (int j = 0; j < 16; ++j) {
        float a  = attn[(size_t)(p * 16 + j) * 64 + c];
        float vv = vnn [(size_t)(p * 16 + j) * 64 + c];
        an = fmaf(a, a, an);
        ag = fmaf(a, vv, ag);
    }
    float nrm = fmaxf(sqrtf(an), 1e-12f);
    agg[(size_t)p * 64 + c] = ag / nrm;
}

// ---------------- out = agg @ w_out + b_out ----------------
__global__ __launch_bounds__(256) void k_out(const float* __restrict__ agg,
                                             const float* __restrict__ w_out,
                                             const float* __restrict__ b_out,
                                             float* __restrict__ outp) {
    const int row = blockIdx.x * 256 + threadIdx.x;   // 0..16383
    const int cc  = blockIdx.y;                        // 0..3
    float out[64];
#pragma unroll
    for (int c = 0; c < 64; ++c) out[c] = b_out[cc * 64 + c];
    const float* ar = agg + (size_t)row * 64;
#pragma unroll 1
    for (int k8 = 0; k8 < 8; ++k8) {
        float4 a0 = *(const float4*)(ar + k8 * 8);
        float4 a1 = *(const float4*)(ar + k8 * 8 + 4);
        float xa[8] = {a0.x, a0.y, a0.z, a0.w, a1.x, a1.y, a1.z, a1.w};
#pragma unroll
        for (int k2 = 0; k2 < 8; ++k2) {
            const float* wrow = w_out + (size_t)(k8 * 8 + k2) * 256 + cc * 64;  // uniform
#pragma unroll
            for (int c = 0; c < 64; ++c) out[c] = fmaf(xa[k2], wrow[c], out[c]);
        }
    }
#pragma unroll
    for (int c4 = 0; c4 < 16; ++c4) {
        float4 o = {out[c4*4], out[c4*4+1], out[c4*4+2], out[c4*4+3]};
        *(float4*)(outp + (size_t)row * 256 + cc * 64 + c4 * 4) = o;
    }
}

extern "C" void kernel_launch(void* const* d_in, const int* in_sizes, int n_in,
                              void* d_out, int out_size, void* d_ws, size_t ws_size,
                              hipStream_t stream) {
    const float* x      = (const float*)d_in[0];
    const float* pos    = (const float*)d_in[1];
    const float* w_qkv  = (const float*)d_in[2];
    const float* w_pos1 = (const float*)d_in[3];
    const float* b_pos1 = (const float*)d_in[4];
    const float* w_pos2 = (const float*)d_in[5];
    const float* b_pos2 = (const float*)d_in[6];
    const float* w_att1 = (const float*)d_in[7];
    const float* b_att1 = (const float*)d_in[8];
    const float* w_att2 = (const float*)d_in[9];
    const float* b_att2 = (const float*)d_in[10];
    const float* w_out  = (const float*)d_in[11];
    const float* b_out  = (const float*)d_in[12];
    float* outp = (float*)d_out;

    char* ws = (char*)d_ws;
    float* q    = (float*)(ws);                    //  4 MiB  (becomes q-k in place)
    float* kk   = (float*)(ws + (4ull  << 20));    //  4 MiB
    float* v    = (float*)(ws + (8ull  << 20));    //  4 MiB
    int*   idx  = (int*)  (ws + (12ull << 20));    //  1 MiB
    float* w1t  = (float*)(ws + (13ull << 20));    // 64 KiB
    float* agg  = (float*)(ws + (14ull << 20));    //  4 MiB
    float* attn = (float*)(ws + (18ull << 20));    // 64 MiB
    float* vnn  = (float*)(ws + (82ull << 20));    // 64 MiB   total 146 MiB

    k_transpose_w1<<<dim3(64), dim3(256), 0, stream>>>(w_att1, w1t);
    k_qkv<<<dim3(64, 3), dim3(256), 0, stream>>>(x, w_qkv, q, kk, v);
    k_qmk<<<dim3(1024), dim3(256), 0, stream>>>(q, kk);
    k_knn<<<dim3(16384), dim3(256), 0, stream>>>(pos, idx);
    k_att<<<dim3(1024), dim3(256), 0, stream>>>(q, v, pos, idx,
                                                w_pos1, b_pos1, w_pos2, b_pos2,
                                                w1t, b_att1, w_att2, b_att2,
                                                vnn, attn);
    k_agg<<<dim3(4096), dim3(256), 0, stream>>>(attn, vnn, agg);
    k_out<<<dim3(64, 4), dim3(256), 0, stream>>>(agg, w_out, b_out, outp);
}

// Round 2
// 591.787 us; speedup vs baseline: 1.3682x; 1.3682x over previous
//
#include <hip/hip_runtime.h>
#include <stdint.h>

typedef __attribute__((ext_vector_type(8))) short bf8v;     // 8 bf16 frag (4 VGPR)
typedef __attribute__((ext_vector_type(4))) float f4v;      // MFMA acc / vec ld-st
typedef __attribute__((ext_vector_type(4))) unsigned int u4v;
typedef __attribute__((ext_vector_type(2))) unsigned int u2v;

#define MFMA16(a,b,c) __builtin_amdgcn_mfma_f32_16x16x32_bf16((a),(b),(c),0,0,0)

__device__ __forceinline__ unsigned short f2bf(float f) {
    unsigned u = __float_as_uint(f);
    return (unsigned short)((u + 0x7FFFu + ((u >> 16) & 1u)) >> 16);  // RNE
}
// u16 index into a swizzled bf16 tile, row length L u16s (L>=64):
// XOR bits 3..5 of the k-index with row&7 -> conflict-free ds_read_b128 at row-stride tiles
#define SW(row,k,L) ((row)*(L) + ((k) ^ (((row)&7)<<3)))

// ws layout (bytes)
#define WS_QMK   0u
#define WS_V     4194304u
#define WS_AGG   8388608u
#define WS_IDX   12582912u
#define WS_W1T   13631488u   // [256 hid][64 k]  32768 B  (k_att blob start)
#define WS_W2T   13664256u   // [64 ch][256 k]   32768 B
#define WS_WPT   13697024u   // [64 ch][64 k]     8192 B  (blob = 73728 B)
#define WS_WQK   13705216u   // [128 col][256 k] 65536 B
#define WS_WOUT  13770752u   // [256 col][64 k]  32768 B

// ---------------- prep: bf16 transpose + pre-swizzle weight images ----------------
__global__ __launch_bounds__(256) void k_prep(
    const float* __restrict__ w_qkv, const float* __restrict__ w_pos2,
    const float* __restrict__ w_att1, const float* __restrict__ w_att2,
    const float* __restrict__ w_out, char* __restrict__ ws)
{
    int t = blockIdx.x * 256 + threadIdx.x;
    unsigned short* w1i = (unsigned short*)(ws + WS_W1T);
    unsigned short* w2i = (unsigned short*)(ws + WS_W2T);
    unsigned short* wpi = (unsigned short*)(ws + WS_WPT);
    unsigned short* wqi = (unsigned short*)(ws + WS_WQK);
    unsigned short* woi = (unsigned short*)(ws + WS_WOUT);
    if (t < 16384) {                      // W1T[hid][k] = w_att1[k][hid]
        int hid = t >> 6, k = t & 63;
        w1i[hid*64 + (k ^ ((hid&7)<<3))] = f2bf(w_att1[k*256 + hid]);
    } else if (t < 32768) {               // W2T[ch][k] = w_att2[k][ch]
        int i = t - 16384; int ch = i >> 8, k = i & 255;
        w2i[ch*256 + (k ^ ((ch&7)<<3))] = f2bf(w_att2[k*64 + ch]);
    } else if (t < 36864) {               // WPT[ch][k] = w_pos2[k][ch]
        int i = t - 32768; int ch = i >> 6, k = i & 63;
        wpi[ch*64 + (k ^ ((ch&7)<<3))] = f2bf(w_pos2[k*64 + ch]);
    } else if (t < 69632) {               // WqkvT[col][k]: col<64 -> wq-wk, else wv
        int i = t - 36864; int col = i >> 8, k = i & 255;
        float val = (col < 64) ? (w_qkv[k*192 + col] - w_qkv[k*192 + 64 + col])
                               : w_qkv[k*192 + 128 + (col - 64)];
        wqi[col*256 + (k ^ ((col&7)<<3))] = f2bf(val);
    } else if (t < 86016) {               // WoutT[col][k] = w_out[k][col]
        int i = t - 69632; int col = i >> 6, k = i & 63;
        woi[col*64 + (k ^ ((col&7)<<3))] = f2bf(w_out[k*256 + col]);
    }
}

// ---------------- KNN: wave per point, register top-16 ----------------
__global__ __launch_bounds__(256) void k_knn(const float* __restrict__ pos,
                                             int* __restrict__ idxo) {
    const int wid = threadIdx.x >> 6, lane = threadIdx.x & 63;
    const int pid = blockIdx.x * 4 + wid;
    const int b = pid >> 11, i = pid & 2047;
    const float* pb = pos + (size_t)b * 2048 * 3;
    float xi = pb[i*3], yi = pb[i*3+1], zi = pb[i*3+2];
    float d2i = xi*xi; d2i = fmaf(yi, yi, d2i); d2i = fmaf(zi, zi, d2i);
    unsigned long long key[32];
#pragma unroll
    for (int m = 0; m < 32; ++m) {
        int j = m * 64 + lane;
        float xj = pb[j*3], yj = pb[j*3+1], zj = pb[j*3+2];
        float d2j = xj*xj; d2j = fmaf(yj, yj, d2j); d2j = fmaf(zj, zj, d2j);
        float dot = xi*xj; dot = fmaf(yi, yj, dot); dot = fmaf(zi, zj, dot);
        float sim = 2.0f*dot - d2i - d2j;                 // same arith as r1 (passed)
        unsigned u = __float_as_uint(sim);
        unsigned fk = (u & 0x80000000u) ? ~u : (u | 0x80000000u);
        key[m] = ((unsigned long long)fk << 32) | (unsigned)(0xFFFFFFFFu - (unsigned)j);
    }
    unsigned long long lmax = key[0];
#pragma unroll
    for (int m = 1; m < 32; ++m) lmax = (key[m] > lmax) ? key[m] : lmax;
    int my = 0;
    for (int it = 0; it < 16; ++it) {
        unsigned long long wmax = lmax;
#pragma unroll
        for (int st = 32; st >= 1; st >>= 1) {
            unsigned long long o = __shfl_xor(wmax, st);
            wmax = (o > wmax) ? o : wmax;
        }
        int jw = (int)(0xFFFFFFFFu - (unsigned)(wmax & 0xFFFFFFFFull));
        if (lane == it) my = jw;
        if (lmax == wmax) {               // unique winner lane: remove + recompute
#pragma unroll
            for (int m = 0; m < 32; ++m) if (key[m] == wmax) key[m] = 0ull;
            lmax = key[0];
#pragma unroll
            for (int m = 1; m < 32; ++m) lmax = (key[m] > lmax) ? key[m] : lmax;
        }
    }
    if (lane < 16) idxo[pid * 16 + lane] = b * 2048 + my;
}

// ---------------- qkv: MFMA GEMM  [16384 x 256] @ [256 x 128] -> qmk | v ----------------
__global__ __launch_bounds__(256, 1) void k_qkv(const float* __restrict__ x,
        const char* __restrict__ wimg, float* __restrict__ qmk, float* __restrict__ v) {
    extern __shared__ char smem[];
    unsigned short* WQ = (unsigned short*)smem;            // [128][256] swz, 64KB
    unsigned short* XT = (unsigned short*)(smem + 65536);  // [64][256] swz, 32KB
    const int tid = threadIdx.x, wid = tid >> 6, lane = tid & 63;
    const int q4 = lane >> 4, l15 = lane & 15;
#pragma unroll
    for (int itn = 0; itn < 16; ++itn) {
        int off = itn * 4096 + tid * 16;
        *(u4v*)(smem + off) = *(const u4v*)(wimg + off);
    }
    __syncthreads();
    {   // stage X tile (rows are wave-local -> no barrier needed)
        int r = tid >> 2, k64 = (tid & 3) * 64;
        const float* xr = x + ((size_t)blockIdx.x * 64 + r) * 256 + k64;
#pragma unroll
        for (int c = 0; c < 8; ++c) {
            f4v a = *(const f4v*)(xr + c*8);
            f4v bq = *(const f4v*)(xr + c*8 + 4);
            bf8v s;
            s[0]=(short)f2bf(a[0]); s[1]=(short)f2bf(a[1]); s[2]=(short)f2bf(a[2]); s[3]=(short)f2bf(a[3]);
            s[4]=(short)f2bf(bq[0]); s[5]=(short)f2bf(bq[1]); s[6]=(short)f2bf(bq[2]); s[7]=(short)f2bf(bq[3]);
            *(bf8v*)&XT[SW(r, k64 + c*8, 256)] = s;
        }
    }
    f4v z = {0.f,0.f,0.f,0.f};
    f4v acc[8];
#pragma unroll
    for (int n = 0; n < 8; ++n) acc[n] = z;
    const int arow = wid*16 + l15;
#pragma unroll
    for (int ks = 0; ks < 8; ++ks) {
        int k0 = ks*32 + q4*8;
        bf8v a = *(const bf8v*)&XT[SW(arow, k0, 256)];
#pragma unroll
        for (int nt = 0; nt < 8; ++nt) {
            bf8v bq = *(const bf8v*)&WQ[SW(nt*16 + l15, k0, 256)];
            acc[nt] = MFMA16(a, bq, acc[nt]);
        }
    }
    size_t rbase = (size_t)blockIdx.x * 64 + wid*16 + q4*4;
#pragma unroll
    for (int nt = 0; nt < 8; ++nt) {
        int col = nt*16 + l15;
#pragma unroll
        for (int j = 0; j < 4; ++j) {
            if (nt < 4) qmk[(rbase + j)*64 + col] = acc[nt][j];
            else        v[(rbase + j)*64 + (col - 64)] = acc[nt][j];
        }
    }
}

// ---------------- fused attention: wave per point, weights LDS-resident ----------------
__global__ __launch_bounds__(256, 1) void k_att(
    const float* __restrict__ qmk, const float* __restrict__ v,
    const float* __restrict__ pos, const int* __restrict__ idx,
    const float* __restrict__ w_pos1, const float* __restrict__ b_pos1,
    const float* __restrict__ b_pos2, const float* __restrict__ b_att1,
    const float* __restrict__ b_att2, const char* __restrict__ wblob,
    float* __restrict__ agg)
{
    extern __shared__ char smem[];
    unsigned short* W1T = (unsigned short*)smem;            // [256][64] swz
    unsigned short* W2T = (unsigned short*)(smem + 32768);  // [64][256] swz
    unsigned short* WPT = (unsigned short*)(smem + 65536);  // [64][64]  swz
    const int tid = threadIdx.x, wid = tid >> 6, lane = tid & 63;
    const int q4 = lane >> 4, l15 = lane & 15;
    char* wb = smem + 73728 + wid * 16640;                  // per-wave scratch
    unsigned short* PH = (unsigned short*)wb;               // [16][64] bf16 swz
    unsigned short* H  = (unsigned short*)(wb + 2048);      // [16][64] bf16 swz
    float*          RV = (float*)(wb + 4096);               // [16][68] f32 (rpe then vnn)
    unsigned short* C1 = (unsigned short*)(wb + 8448);      // [16][256] bf16 swz

#pragma unroll
    for (int itn = 0; itn < 18; ++itn) {                    // stage 73728B of weights
        int off = itn * 4096 + tid * 16;
        *(u4v*)(smem + off) = *(const u4v*)(wblob + off);
    }
    __syncthreads();                                        // only barrier in kernel

    float bp2[16], ba2[16];
#pragma unroll
    for (int mt = 0; mt < 4; ++mt)
#pragma unroll
        for (int j = 0; j < 4; ++j) {
            int ch = mt*16 + q4*4 + j;
            bp2[mt*4+j] = b_pos2[ch];
            ba2[mt*4+j] = b_att2[ch];
        }

    const int r4 = lane >> 2, c16 = (lane & 3) * 16;
    f4v z = {0.f,0.f,0.f,0.f};

    for (int it = 0; it < 16; ++it) {
        const int point = (blockIdx.x * 4 + wid) * 16 + it;
        // ---- phase1: ph = relu(rel @ w_pos1 + b_pos1), lane=(row, 16-hid chunk) ----
        {
            int grow = point * 16 + r4;
            int flat = idx[grow];
            float cx = pos[point*3], cy = pos[point*3+1], cz = pos[point*3+2];
            float r0 = pos[flat*3] - cx, r1 = pos[flat*3+1] - cy, r2 = pos[flat*3+2] - cz;
            bf8v lo, hi;
#pragma unroll
            for (int i = 0; i < 16; ++i) {
                int h = c16 + i;
                float t = fmaf(r2, w_pos1[128+h], fmaf(r1, w_pos1[64+h], fmaf(r0, w_pos1[h], b_pos1[h])));
                t = fmaxf(t, 0.f);
                if (i < 8) lo[i] = (short)f2bf(t); else hi[i-8] = (short)f2bf(t);
            }
            *(bf8v*)&PH[SW(r4, c16, 64)] = lo;
            *(bf8v*)&PH[SW(r4, c16+8, 64)] = hi;
        }
        // ---- GEMM0': rpe^T[ch][row] = WPT @ PH^T  (M=64,N=16,K=64) ----
        {
            f4v ga[4];
#pragma unroll
            for (int mt = 0; mt < 4; ++mt) ga[mt] = z;
#pragma unroll
            for (int ks = 0; ks < 2; ++ks) {
                int k0 = ks*32 + q4*8;
                bf8v bfr = *(const bf8v*)&PH[SW(l15, k0, 64)];
#pragma unroll
                for (int mt = 0; mt < 4; ++mt)
                    ga[mt] = MFMA16(*(const bf8v*)&WPT[SW(mt*16 + l15, k0, 64)], bfr, ga[mt]);
            }
#pragma unroll
            for (int mt = 0; mt < 4; ++mt) {
                f4v o;
#pragma unroll
                for (int j = 0; j < 4; ++j) o[j] = ga[mt][j] + bp2[mt*4+j];
                *(f4v*)&RV[l15*68 + mt*16 + q4*4] = o;      // rpe, padded rows (no conflict)
            }
        }
        // ---- phase3: h = qmk[flat]+rpe -> H(bf16); vnn = v[flat]+rpe -> RV (overwrite) ----
        {
            int grow = point * 16 + r4;
            int flat = idx[grow];
            f4v rp[4], qk[4];
#pragma unroll
            for (int i = 0; i < 4; ++i) rp[i] = *(const f4v*)&RV[r4*68 + c16 + i*4];
#pragma unroll
            for (int i = 0; i < 4; ++i) qk[i] = *(const f4v*)(qmk + (size_t)flat*64 + c16 + i*4);
            bf8v lo, hi;
#pragma unroll
            for (int i = 0; i < 16; ++i) {
                float hv = rp[i>>2][i&3] + qk[i>>2][i&3];
                if (i < 8) lo[i] = (short)f2bf(hv); else hi[i-8] = (short)f2bf(hv);
            }
            *(bf8v*)&H[SW(r4, c16, 64)] = lo;
            *(bf8v*)&H[SW(r4, c16+8, 64)] = hi;
#pragma unroll
            for (int i = 0; i < 4; ++i) {
                f4v vv = *(const f4v*)(v + (size_t)flat*64 + c16 + i*4);
                f4v o;
#pragma unroll
                for (int j = 0; j < 4; ++j) o[j] = vv[j] + rp[i][j];
                *(f4v*)&RV[r4*68 + c16 + i*4] = o;          // vnn overwrites rpe slots
            }
        }
        // ---- GEMM1': C1^T[hid][row] = W1T @ H^T  (M=256,N=16,K=64), relu -> C1 bf16 ----
        {
            f4v cc[16];
#pragma unroll
            for (int mt = 0; mt < 16; ++mt) cc[mt] = z;
#pragma unroll
            for (int ks = 0; ks < 2; ++ks) {
                int k0 = ks*32 + q4*8;
                bf8v bfr = *(const bf8v*)&H[SW(l15, k0, 64)];
#pragma unroll
                for (int mt = 0; mt < 16; ++mt)
                    cc[mt] = MFMA16(*(const bf8v*)&W1T[SW(mt*16 + l15, k0, 64)], bfr, cc[mt]);
            }
#pragma unroll
            for (int mt = 0; mt < 16; ++mt) {
                f4v ba = *(const f4v*)(b_att1 + mt*16 + q4*4);
                float t0 = fmaxf(cc[mt][0]+ba[0], 0.f), t1 = fmaxf(cc[mt][1]+ba[1], 0.f);
                float t2 = fmaxf(cc[mt][2]+ba[2], 0.f), t3 = fmaxf(cc[mt][3]+ba[3], 0.f);
                u2v pp;
                pp[0] = (unsigned)f2bf(t0) | ((unsigned)f2bf(t1) << 16);
                pp[1] = (unsigned)f2bf(t2) | ((unsigned)f2bf(t3) << 16);
                *(u2v*)&C1[SW(l15, mt*16 + q4*4, 256)] = pp;  // 4 bf16, stays in 8-chunk
            }
        }
        // ---- GEMM2': sim^T[ch][row] = W2T @ C1^T (M=64,N=16,K=256) + softmax/norm/agg ----
        {
            f4v ss[4];
#pragma unroll
            for (int mt = 0; mt < 4; ++mt) ss[mt] = z;
#pragma unroll
            for (int ks = 0; ks < 8; ++ks) {
                int k0 = ks*32 + q4*8;
                bf8v bfr = *(const bf8v*)&C1[SW(l15, k0, 256)];
#pragma unroll
                for (int mt = 0; mt < 4; ++mt)
                    ss[mt] = MFMA16(*(const bf8v*)&W2T[SW(mt*16 + l15, k0, 256)], bfr, ss[mt]);
            }
            // softmax over 64 ch of row l15: in-lane 16 + quarters via xor16/32
            float e[16];
            float mx = -3.4e38f;
#pragma unroll
            for (int i = 0; i < 16; ++i) { e[i] = ss[i>>2][i&3] + ba2[i]; mx = fmaxf(mx, e[i]); }
            mx = fmaxf(mx, __shfl_xor(mx, 16));
            mx = fmaxf(mx, __shfl_xor(mx, 32));
            float sum = 0.f;
#pragma unroll
            for (int i = 0; i < 16; ++i) { e[i] = __expf(e[i] - mx); sum += e[i]; }
            sum += __shfl_xor(sum, 16);
            sum += __shfl_xor(sum, 32);
            float inv = 1.0f / sum;
            float nn[16];
#pragma unroll
            for (int i = 0; i < 16; ++i) { e[i] *= inv; nn[i] = e[i]*e[i]; }
#pragma unroll
            for (int st = 1; st <= 8; st <<= 1)               // L2 norm over 16 neighbors
#pragma unroll
                for (int i = 0; i < 16; ++i) nn[i] += __shfl_xor(nn[i], st);
            float ag[16];
#pragma unroll
            for (int mt = 0; mt < 4; ++mt) {
                f4v vn = *(const f4v*)&RV[l15*68 + mt*16 + q4*4];
#pragma unroll
                for (int j = 0; j < 4; ++j) {
                    int i = mt*4 + j;
                    float a = e[i] / fmaxf(sqrtf(nn[i]), 1e-12f);
                    ag[i] = a * vn[j];
                }
            }
#pragma unroll
            for (int st = 1; st <= 8; st <<= 1)               // agg over 16 neighbors
#pragma unroll
                for (int i = 0; i < 16; ++i) ag[i] += __shfl_xor(ag[i], st);
            if (l15 == 0) {
#pragma unroll
                for (int mt = 0; mt < 4; ++mt) {
                    f4v o;
#pragma unroll
                    for (int j = 0; j < 4; ++j) o[j] = ag[mt*4+j];
                    *(f4v*)(agg + (size_t)point*64 + mt*16 + q4*4) = o;
                }
            }
        }
    }
}

// ---------------- out: MFMA GEMM [16384 x 64] @ [64 x 256] + b_out ----------------
__global__ __launch_bounds__(256, 1) void k_out(const float* __restrict__ agg,
        const char* __restrict__ wimg, const float* __restrict__ b_out,
        float* __restrict__ outp) {
    extern __shared__ char smem[];
    unsigned short* WO = (unsigned short*)smem;            // [256][64] swz
    unsigned short* AT = (unsigned short*)(smem + 32768);  // [64][64]  swz
    const int tid = threadIdx.x, wid = tid >> 6, lane = tid & 63;
    const int q4 = lane >> 4, l15 = lane & 15;
#pragma unroll
    for (int itn = 0; itn < 8; ++itn) {
        int off = itn * 4096 + tid * 16;
        *(u4v*)(smem + off) = *(const u4v*)(wimg + off);
    }
    __syncthreads();
    {
        int r = tid >> 2, k16 = (tid & 3) * 16;
        const float* ar = agg + ((size_t)blockIdx.x * 64 + r) * 64 + k16;
        bf8v lo, hi;
#pragma unroll
        for (int i = 0; i < 16; ++i) {
            float t = ar[i];
            if (i < 8) lo[i] = (short)f2bf(t); else hi[i-8] = (short)f2bf(t);
        }
        *(bf8v*)&AT[SW(r, k16, 64)] = lo;
        *(bf8v*)&AT[SW(r, k16+8, 64)] = hi;
    }
    f4v z = {0.f,0.f,0.f,0.f};
    f4v acc[16];
#pragma unroll
    for (int nt = 0; nt < 16; ++nt) acc[nt] = z;
#pragma unroll
    for (int ks = 0; ks < 2; ++ks) {
        int k0 = ks*32 + q4*8;
        bf8v a = *(const bf8v*)&AT[SW(wid*16 + l15, k0, 64)];
#pragma unroll
        for (int nt = 0; nt < 16; ++nt) {
            bf8v bq = *(const bf8v*)&WO[SW(nt*16 + l15, k0, 64)];
            acc[nt] = MFMA16(a, bq, acc[nt]);
        }
    }
    size_t rbase = (size_t)blockIdx.x * 64 + wid*16 + q4*4;
#pragma unroll
    for (int nt = 0; nt < 16; ++nt) {
        int col = nt*16 + l15;
        float bo = b_out[col];
#pragma unroll
        for (int j = 0; j < 4; ++j)
            outp[(rbase + j)*256 + col] = acc[nt][j] + bo;
    }
}

extern "C" void kernel_launch(void* const* d_in, const int* in_sizes, int n_in,
                              void* d_out, int out_size, void* d_ws, size_t ws_size,
                              hipStream_t stream) {
    (void)in_sizes; (void)n_in; (void)out_size; (void)ws_size;
    const float* x      = (const float*)d_in[0];
    const float* pos    = (const float*)d_in[1];
    const float* w_qkv  = (const float*)d_in[2];
    const float* w_pos1 = (const float*)d_in[3];
    const float* b_pos1 = (const float*)d_in[4];
    const float* w_pos2 = (const float*)d_in[5];
    const float* b_pos2 = (const float*)d_in[6];
    const float* w_att1 = (const float*)d_in[7];
    const float* b_att1 = (const float*)d_in[8];
    const float* w_att2 = (const float*)d_in[9];
    const float* b_att2 = (const float*)d_in[10];
    const float* w_out  = (const float*)d_in[11];
    const float* b_out  = (const float*)d_in[12];
    float* outp = (float*)d_out;

    char* ws = (char*)d_ws;
    float* qmk = (float*)(ws + WS_QMK);
    float* v   = (float*)(ws + WS_V);
    float* agg = (float*)(ws + WS_AGG);
    int*   idx = (int*)(ws + WS_IDX);

    k_prep<<<dim3(336), dim3(256), 0, stream>>>(w_qkv, w_pos2, w_att1, w_att2, w_out, ws);
    k_knn<<<dim3(4096), dim3(256), 0, stream>>>(pos, idx);
    k_qkv<<<dim3(256), dim3(256), 98304, stream>>>(x, ws + WS_WQK, qmk, v);
    k_att<<<dim3(256), dim3(256), 140288, stream>>>(qmk, v, pos, idx,
                                                    w_pos1, b_pos1, b_pos2, b_att1, b_att2,
                                                    ws + WS_W1T, agg);
    k_out<<<dim3(256), dim3(256), 40960, stream>>>(agg, ws + WS_WOUT, b_out, outp);
}

// Round 6
// 581.628 us; speedup vs baseline: 1.3921x; 1.0175x over previous
//
#include <hip/hip_runtime.h>
#include <stdint.h>

typedef __attribute__((ext_vector_type(8))) short bf8v;     // 8 bf16 frag (4 VGPR)
typedef __attribute__((ext_vector_type(4))) float f4v;      // MFMA acc / vec ld-st
typedef __attribute__((ext_vector_type(4))) unsigned int u4v;
typedef __attribute__((ext_vector_type(2))) unsigned int u2v;

#define MFMA16(a,b,c) __builtin_amdgcn_mfma_f32_16x16x32_bf16((a),(b),(c),0,0,0)

__device__ __forceinline__ unsigned short f2bf(float f) {
    unsigned u = __float_as_uint(f);
    return (unsigned short)((u + 0x7FFFu + ((u >> 16) & 1u)) >> 16);  // RNE
}
// u16 index into a swizzled bf16 tile, row length L u16s (L>=64):
// XOR bits 3..5 of the k-index with row&7 -> spreads a frag-read over all 32 banks
#define SW(row,k,L) ((row)*(L) + ((k) ^ (((row)&7)<<3)))

// ws layout (bytes)
#define WS_QMK   0u
#define WS_V     4194304u
#define WS_AGG   8388608u
#define WS_IDX   12582912u
#define WS_W1T   13631488u   // [256 hid][64 k]  32768 B  (k_att blob start)
#define WS_W2T   13664256u   // [64 ch][256 k]   32768 B
#define WS_WPT   13697024u   // [64 ch][64 k]     8192 B  (blob = 73728 B)
#define WS_WQK   13705216u   // [128 col][256 k] 65536 B
#define WS_WOUT  13770752u   // [256 col][64 k]  32768 B

// ---------------- prep: bf16 transpose + pre-swizzle weight images ----------------
__global__ __launch_bounds__(256) void k_prep(
    const float* __restrict__ w_qkv, const float* __restrict__ w_pos2,
    const float* __restrict__ w_att1, const float* __restrict__ w_att2,
    const float* __restrict__ w_out, char* __restrict__ ws)
{
    int t = blockIdx.x * 256 + threadIdx.x;
    unsigned short* w1i = (unsigned short*)(ws + WS_W1T);
    unsigned short* w2i = (unsigned short*)(ws + WS_W2T);
    unsigned short* wpi = (unsigned short*)(ws + WS_WPT);
    unsigned short* wqi = (unsigned short*)(ws + WS_WQK);
    unsigned short* woi = (unsigned short*)(ws + WS_WOUT);
    if (t < 16384) {                      // W1T[hid][k] = w_att1[k][hid]
        int hid = t >> 6, k = t & 63;
        w1i[hid*64 + (k ^ ((hid&7)<<3))] = f2bf(w_att1[k*256 + hid]);
    } else if (t < 32768) {               // W2T[ch][k] = w_att2[k][ch]
        int i = t - 16384; int ch = i >> 8, k = i & 255;
        w2i[ch*256 + (k ^ ((ch&7)<<3))] = f2bf(w_att2[k*64 + ch]);
    } else if (t < 36864) {               // WPT[ch][k] = w_pos2[k][ch]
        int i = t - 32768; int ch = i >> 6, k = i & 63;
        wpi[ch*64 + (k ^ ((ch&7)<<3))] = f2bf(w_pos2[k*64 + ch]);
    } else if (t < 69632) {               // WqkvT[col][k]: col<64 -> wq-wk, else wv
        int i = t - 36864; int col = i >> 8, k = i & 255;
        float val = (col < 64) ? (w_qkv[k*192 + col] - w_qkv[k*192 + 64 + col])
                               : w_qkv[k*192 + 128 + (col - 64)];
        wqi[col*256 + (k ^ ((col&7)<<3))] = f2bf(val);
    } else if (t < 86016) {               // WoutT[col][k] = w_out[k][col]
        int i = t - 69632; int col = i >> 6, k = i & 63;
        woi[col*64 + (k ^ ((col&7)<<3))] = f2bf(w_out[k*256 + col]);
    }
}

// ---------------- KNN: wave per point, register top-16 ----------------
__global__ __launch_bounds__(256) void k_knn(const float* __restrict__ pos,
                                             int* __restrict__ idxo) {
    const int wid = threadIdx.x >> 6, lane = threadIdx.x & 63;
    const int pid = blockIdx.x * 4 + wid;
    const int b = pid >> 11, i = pid & 2047;
    const float* pb = pos + (size_t)b * 2048 * 3;
    float xi = pb[i*3], yi = pb[i*3+1], zi = pb[i*3+2];
    float d2i = xi*xi; d2i = fmaf(yi, yi, d2i); d2i = fmaf(zi, zi, d2i);
    unsigned long long key[32];
#pragma unroll
    for (int m = 0; m < 32; ++m) {
        int j = m * 64 + lane;
        float xj = pb[j*3], yj = pb[j*3+1], zj = pb[j*3+2];
        float d2j = xj*xj; d2j = fmaf(yj, yj, d2j); d2j = fmaf(zj, zj, d2j);
        float dot = xi*xj; dot = fmaf(yi, yj, dot); dot = fmaf(zi, zj, dot);
        float sim = 2.0f*dot - d2i - d2j;
        unsigned u = __float_as_uint(sim);
        unsigned fk = (u & 0x80000000u) ? ~u : (u | 0x80000000u);
        key[m] = ((unsigned long long)fk << 32) | (unsigned)(0xFFFFFFFFu - (unsigned)j);
    }
    unsigned long long lmax = key[0];
#pragma unroll
    for (int m = 1; m < 32; ++m) lmax = (key[m] > lmax) ? key[m] : lmax;
    int my = 0;
    for (int it = 0; it < 16; ++it) {
        unsigned long long wmax = lmax;
#pragma unroll
        for (int st = 32; st >= 1; st >>= 1) {
            unsigned long long o = __shfl_xor(wmax, st);
            wmax = (o > wmax) ? o : wmax;
        }
        int jw = (int)(0xFFFFFFFFu - (unsigned)(wmax & 0xFFFFFFFFull));
        if (lane == it) my = jw;
        if (lmax == wmax) {               // unique winner lane: remove + recompute
#pragma unroll
            for (int m = 0; m < 32; ++m) if (key[m] == wmax) key[m] = 0ull;
            lmax = key[0];
#pragma unroll
            for (int m = 1; m < 32; ++m) lmax = (key[m] > lmax) ? key[m] : lmax;
        }
    }
    if (lane < 16) idxo[pid * 16 + lane] = b * 2048 + my;
}

// ---------------- qkv: MFMA GEMM  [16384 x 256] @ [256 x 128] -> qmk | v ----------------
__global__ __launch_bounds__(256, 1) void k_qkv(const float* __restrict__ x,
        const char* __restrict__ wimg, float* __restrict__ qmk, float* __restrict__ v) {
    extern __shared__ char smem[];
    unsigned short* WQ = (unsigned short*)smem;            // [128][256] swz, 64KB
    unsigned short* XT = (unsigned short*)(smem + 65536);  // [64][256] swz, 32KB
    const int tid = threadIdx.x, wid = tid >> 6, lane = tid & 63;
    const int q4 = lane >> 4, l15 = lane & 15;
#pragma unroll
    for (int itn = 0; itn < 16; ++itn) {
        int off = itn * 4096 + tid * 16;
        *(u4v*)(smem + off) = *(const u4v*)(wimg + off);
    }
    __syncthreads();
    {   // stage X tile
        int r = tid >> 2, k64 = (tid & 3) * 64;
        const float* xr = x + ((size_t)blockIdx.x * 64 + r) * 256 + k64;
#pragma unroll
        for (int c = 0; c < 8; ++c) {
            f4v a = *(const f4v*)(xr + c*8);
            f4v bq = *(const f4v*)(xr + c*8 + 4);
            bf8v s;
            s[0]=(short)f2bf(a[0]); s[1]=(short)f2bf(a[1]); s[2]=(short)f2bf(a[2]); s[3]=(short)f2bf(a[3]);
            s[4]=(short)f2bf(bq[0]); s[5]=(short)f2bf(bq[1]); s[6]=(short)f2bf(bq[2]); s[7]=(short)f2bf(bq[3]);
            *(bf8v*)&XT[SW(r, k64 + c*8, 256)] = s;
        }
    }
    f4v z = {0.f,0.f,0.f,0.f};
    f4v acc[8];
#pragma unroll
    for (int n = 0; n < 8; ++n) acc[n] = z;
    const int arow = wid*16 + l15;
#pragma unroll
    for (int ks = 0; ks < 8; ++ks) {
        int k0 = ks*32 + q4*8;
        bf8v a = *(const bf8v*)&XT[SW(arow, k0, 256)];
#pragma unroll
        for (int nt = 0; nt < 8; ++nt) {
            bf8v bq = *(const bf8v*)&WQ[SW(nt*16 + l15, k0, 256)];
            acc[nt] = MFMA16(a, bq, acc[nt]);
        }
    }
    size_t rbase = (size_t)blockIdx.x * 64 + wid*16 + q4*4;
#pragma unroll
    for (int nt = 0; nt < 8; ++nt) {
        int col = nt*16 + l15;
#pragma unroll
        for (int j = 0; j < 4; ++j) {
            if (nt < 4) qmk[(rbase + j)*64 + col] = acc[nt][j];
            else        v[(rbase + j)*64 + (col - 64)] = acc[nt][j];
        }
    }
}

// ---------------- fused attention: 8 waves/block, wave = one point at a time ----------------
// All phases wave-local (one barrier total). Weights LDS-resident; biases folded
// into MFMA acc init; softmax/L2norm/agg fully in-register via shfl_xor.
__global__ __launch_bounds__(512, 2) void k_att(
    const float* __restrict__ qmk, const float* __restrict__ v,
    const float* __restrict__ pos, const int* __restrict__ idx,
    const float* __restrict__ w_pos1, const float* __restrict__ b_pos1,
    const float* __restrict__ b_pos2, const float* __restrict__ b_att1,
    const float* __restrict__ b_att2, const char* __restrict__ wblob,
    float* __restrict__ agg)
{
    extern __shared__ char smem[];
    unsigned short* W1T = (unsigned short*)smem;            // [256][64] swz
    unsigned short* W2T = (unsigned short*)(smem + 32768);  // [64][256] swz
    unsigned short* WPT = (unsigned short*)(smem + 65536);  // [64][64]  swz
    const int tid = threadIdx.x, wid = tid >> 6, lane = tid & 63;
    const int q4 = lane >> 4, l15 = lane & 15;
    const int r4 = lane >> 2, c16 = (lane & 3) * 16;
    char* wb = smem + 73728 + wid * 10240;                  // per-wave scratch
    unsigned short* P  = (unsigned short*)wb;               // [16][256] bf16 swz
    unsigned short* PH = (unsigned short*)wb;               // [16][64]  (aliases P head)
    unsigned short* H  = (unsigned short*)(wb + 8192);      // [16][64]  bf16 swz

#pragma unroll
    for (int it = 0; it < 9; ++it) {                        // stage 73728B of weights
        int off = it * 8192 + tid * 16;
        *(u4v*)(smem + off) = *(const u4v*)(wblob + off);
    }
    __syncthreads();                                        // only barrier in kernel

#pragma unroll 1
    for (int g = 0; g < 8; ++g) {
        const int p = (blockIdx.x * 8 + wid) * 8 + g;
        const int rowbase = p * 16;

        // ---- gathers issued early (latency hidden under PH + GEMM0) ----
        const int flat_l = idx[rowbase + l15];
        f4v qk[4], vv[4];
#pragma unroll
        for (int mt = 0; mt < 4; ++mt)
            qk[mt] = *(const f4v*)(qmk + (size_t)flat_l * 64 + mt*16 + q4*4);
#pragma unroll
        for (int mt = 0; mt < 4; ++mt)
            vv[mt] = *(const f4v*)(v + (size_t)flat_l * 64 + mt*16 + q4*4);

        // ---- PH = relu(rel @ w_pos1 + b_pos1): lane = (row r4, 16-hid chunk c16) ----
        {
            int flat_r = idx[rowbase + r4];
            float cx = pos[p*3], cy = pos[p*3+1], cz = pos[p*3+2];
            float r0 = pos[flat_r*3] - cx, r1 = pos[flat_r*3+1] - cy, r2v = pos[flat_r*3+2] - cz;
            bf8v lo, hi;
#pragma unroll
            for (int u = 0; u < 4; ++u) {
                f4v w0 = *(const f4v*)(w_pos1 + c16 + u*4);
                f4v w1 = *(const f4v*)(w_pos1 + 64 + c16 + u*4);
                f4v w2 = *(const f4v*)(w_pos1 + 128 + c16 + u*4);
                f4v bb = *(const f4v*)(b_pos1 + c16 + u*4);
#pragma unroll
                for (int j = 0; j < 4; ++j) {
                    float t = fmaf(r2v, w2[j], fmaf(r1, w1[j], fmaf(r0, w0[j], bb[j])));
                    t = fmaxf(t, 0.f);
                    if (u < 2) lo[u*4+j] = (short)f2bf(t);
                    else       hi[(u-2)*4+j] = (short)f2bf(t);
                }
            }
            *(bf8v*)&PH[SW(r4, c16, 64)] = lo;
            *(bf8v*)&PH[SW(r4, c16+8, 64)] = hi;
        }

        // ---- GEMM0: rpe[ch][row] = WPT @ PH^T, acc init = b_pos2 ----
        f4v rp[4];
#pragma unroll
        for (int mt = 0; mt < 4; ++mt) rp[mt] = *(const f4v*)(b_pos2 + mt*16 + q4*4);
#pragma unroll
        for (int ks = 0; ks < 2; ++ks) {
            int k0 = ks*32 + q4*8;
            bf8v bfr = *(const bf8v*)&PH[SW(l15, k0, 64)];
#pragma unroll
            for (int mt = 0; mt < 4; ++mt)
                rp[mt] = MFMA16(*(const bf8v*)&WPT[SW(mt*16+l15, k0, 64)], bfr, rp[mt]);
        }

        // ---- h = rpe + qmk[flat] -> H (bf16);  vn = rpe + v[flat] (regs) ----
        f4v vn[4];
#pragma unroll
        for (int mt = 0; mt < 4; ++mt) {
            float h0 = rp[mt][0] + qk[mt][0], h1 = rp[mt][1] + qk[mt][1];
            float h2 = rp[mt][2] + qk[mt][2], h3 = rp[mt][3] + qk[mt][3];
            u2v pp;
            pp[0] = (unsigned)f2bf(h0) | ((unsigned)f2bf(h1) << 16);
            pp[1] = (unsigned)f2bf(h2) | ((unsigned)f2bf(h3) << 16);
            *(u2v*)&H[SW(l15, mt*16 + q4*4, 64)] = pp;
            vn[mt] = rp[mt] + vv[mt];
        }

        // ---- GEMM1: c1[hid][row] = W1T @ H^T, acc init = b_att1 ----
        f4v c1[16];
#pragma unroll
        for (int mt = 0; mt < 16; ++mt) c1[mt] = *(const f4v*)(b_att1 + mt*16 + q4*4);
#pragma unroll
        for (int ks = 0; ks < 2; ++ks) {
            int k0 = ks*32 + q4*8;
            bf8v bfr = *(const bf8v*)&H[SW(l15, k0, 64)];
#pragma unroll
            for (int mt = 0; mt < 16; ++mt)
                c1[mt] = MFMA16(*(const bf8v*)&W1T[SW(mt*16+l15, k0, 64)], bfr, c1[mt]);
        }

        // ---- P = relu(c1) -> bf16 (overwrites PH region; GEMM0 is done) ----
#pragma unroll
        for (int mt = 0; mt < 16; ++mt) {
            float t0 = fmaxf(c1[mt][0], 0.f), t1 = fmaxf(c1[mt][1], 0.f);
            float t2 = fmaxf(c1[mt][2], 0.f), t3 = fmaxf(c1[mt][3], 0.f);
            u2v pp;
            pp[0] = (unsigned)f2bf(t0) | ((unsigned)f2bf(t1) << 16);
            pp[1] = (unsigned)f2bf(t2) | ((unsigned)f2bf(t3) << 16);
            *(u2v*)&P[SW(l15, mt*16 + q4*4, 256)] = pp;
        }

        // ---- GEMM2: sim[ch][row] = W2T @ P^T, acc init = b_att2 ----
        f4v ss[4];
#pragma unroll
        for (int mt = 0; mt < 4; ++mt) ss[mt] = *(const f4v*)(b_att2 + mt*16 + q4*4);
#pragma unroll
        for (int ks = 0; ks < 8; ++ks) {
            int k0 = ks*32 + q4*8;
            bf8v bfr = *(const bf8v*)&P[SW(l15, k0, 256)];
#pragma unroll
            for (int mt = 0; mt < 4; ++mt)
                ss[mt] = MFMA16(*(const bf8v*)&W2T[SW(mt*16+l15, k0, 256)], bfr, ss[mt]);
        }

        // ---- softmax over 64 ch (in-lane 16 + xor16/32), L2norm+agg over rows (xor1..8) ----
        float e[16]; float mx = -3.4e38f;
#pragma unroll
        for (int i = 0; i < 16; ++i) { e[i] = ss[i>>2][i&3]; mx = fmaxf(mx, e[i]); }
        mx = fmaxf(mx, __shfl_xor(mx, 16));
        mx = fmaxf(mx, __shfl_xor(mx, 32));
        float sum = 0.f;
#pragma unroll
        for (int i = 0; i < 16; ++i) { e[i] = __expf(e[i] - mx); sum += e[i]; }
        sum += __shfl_xor(sum, 16);
        sum += __shfl_xor(sum, 32);
        float inv = 1.0f / sum;
        float nn[16], av[16];
#pragma unroll
        for (int i = 0; i < 16; ++i) {
            e[i] *= inv;
            nn[i] = e[i] * e[i];
            av[i] = e[i] * vn[i>>2][i&3];
        }
#pragma unroll
        for (int st = 1; st <= 8; st <<= 1) {
#pragma unroll
            for (int i = 0; i < 16; ++i) {
                nn[i] += __shfl_xor(nn[i], st);
                av[i] += __shfl_xor(av[i], st);
            }
        }
        if (l15 == 0) {
#pragma unroll
            for (int mt = 0; mt < 4; ++mt) {
                f4v o;
#pragma unroll
                for (int j = 0; j < 4; ++j)
                    o[j] = av[mt*4+j] / fmaxf(sqrtf(nn[mt*4+j]), 1e-12f);
                *(f4v*)(agg + (size_t)p*64 + mt*16 + q4*4) = o;
            }
        }
    }
}

// ---------------- out: MFMA GEMM [16384 x 64] @ [64 x 256] + b_out ----------------
__global__ __launch_bounds__(256, 1) void k_out(const float* __restrict__ agg,
        const char* __restrict__ wimg, const float* __restrict__ b_out,
        float* __restrict__ outp) {
    extern __shared__ char smem[];
    unsigned short* WO = (unsigned short*)smem;            // [256][64] swz
    unsigned short* AT = (unsigned short*)(smem + 32768);  // [64][64]  swz
    const int tid = threadIdx.x, wid = tid >> 6, lane = tid & 63;
    const int q4 = lane >> 4, l15 = lane & 15;
#pragma unroll
    for (int itn = 0; itn < 8; ++itn) {
        int off = itn * 4096 + tid * 16;
        *(u4v*)(smem + off) = *(const u4v*)(wimg + off);
    }
    __syncthreads();
    {
        int r = tid >> 2, k16 = (tid & 3) * 16;
        const float* ar = agg + ((size_t)blockIdx.x * 64 + r) * 64 + k16;
        bf8v lo, hi;
#pragma unroll
        for (int i = 0; i < 16; ++i) {
            float t = ar[i];
            if (i < 8) lo[i] = (short)f2bf(t); else hi[i-8] = (short)f2bf(t);
        }
        *(bf8v*)&AT[SW(r, k16, 64)] = lo;
        *(bf8v*)&AT[SW(r, k16+8, 64)] = hi;
    }
    f4v z = {0.f,0.f,0.f,0.f};
    f4v acc[16];
#pragma unroll
    for (int nt = 0; nt < 16; ++nt) acc[nt] = z;
#pragma unroll
    for (int ks = 0; ks < 2; ++ks) {
        int k0 = ks*32 + q4*8;
        bf8v a = *(const bf8v*)&AT[SW(wid*16 + l15, k0, 64)];
#pragma unroll
        for (int nt = 0; nt < 16; ++nt) {
            bf8v bq = *(const bf8v*)&WO[SW(nt*16 + l15, k0, 64)];
            acc[nt] = MFMA16(a, bq, acc[nt]);
        }
    }
    size_t rbase = (size_t)blockIdx.x * 64 + wid*16 + q4*4;
#pragma unroll
    for (int nt = 0; nt < 16; ++nt) {
        int col = nt*16 + l15;
        float bo = b_out[col];
#pragma unroll
        for (int j = 0; j < 4; ++j)
            outp[(rbase + j)*256 + col] = acc[nt][j] + bo;
    }
}

extern "C" void kernel_launch(void* const* d_in, const int* in_sizes, int n_in,
                              void* d_out, int out_size, void* d_ws, size_t ws_size,
                              hipStream_t stream) {
    (void)in_sizes; (void)n_in; (void)out_size; (void)ws_size;
    const float* x      = (const float*)d_in[0];
    const float* pos    = (const float*)d_in[1];
    const float* w_qkv  = (const float*)d_in[2];
    const float* w_pos1 = (const float*)d_in[3];
    const float* b_pos1 = (const float*)d_in[4];
    const float* w_pos2 = (const float*)d_in[5];
    const float* b_pos2 = (const float*)d_in[6];
    const float* w_att1 = (const float*)d_in[7];
    const float* b_att1 = (const float*)d_in[8];
    const float* w_att2 = (const float*)d_in[9];
    const float* b_att2 = (const float*)d_in[10];
    const float* w_out  = (const float*)d_in[11];
    const float* b_out  = (const float*)d_in[12];
    float* outp = (float*)d_out;

    char* ws = (char*)d_ws;
    float* qmk = (float*)(ws + WS_QMK);
    float* v   = (float*)(ws + WS_V);
    float* agg = (float*)(ws + WS_AGG);
    int*   idx = (int*)(ws + WS_IDX);

    k_prep<<<dim3(336), dim3(256), 0, stream>>>(w_qkv, w_pos2, w_att1, w_att2, w_out, ws);
    k_knn<<<dim3(4096), dim3(256), 0, stream>>>(pos, idx);
    k_qkv<<<dim3(256), dim3(256), 98304, stream>>>(x, ws + WS_WQK, qmk, v);
    k_att<<<dim3(256), dim3(512), 155648, stream>>>(qmk, v, pos, idx,
                                                    w_pos1, b_pos1, b_pos2, b_att1, b_att2,
                                                    ws + WS_W1T, agg);
    k_out<<<dim3(256), dim3(256), 40960, stream>>>(agg, ws + WS_WOUT, b_out, outp);
}